// Round 4
// baseline (28.421 us; speedup 1.0000x reference)
//
#include <hip/hip_runtime.h>
#include <hip/hip_bf16.h>

#define HID   64
#define NHD   8
#define IT    16          // i's per block
#define WAVES 8
#define JTW   32          // j's per wave (2 MFMA tiles of 16)
#define JT    (WAVES*JTW) // 256 j's per block

typedef __attribute__((ext_vector_type(8))) short bf16x8;
typedef __attribute__((ext_vector_type(4))) float f32x4;

static __device__ __forceinline__ short f2bf(float f) {
  __hip_bfloat16 h = __float2bfloat16(f);
  short s; __builtin_memcpy(&s, &h, sizeof(s));
  return s;
}

// out[b,k,i,j] = sum_h relu( (u_j[h]+b1[h]) - u_i[h] ) * W2[h,k] + b2[k]
// MFMA 16x16x32 bf16, ONE accumulator per i:
//   aLo = W2^T in A-rows 0..7  (rows 8..15 zero)  -> D rows 0..7  = tile0 j's
//   aHi = W2^T in A-rows 8..15 (rows 0..7  zero)  -> D rows 8..15 = tile1 j's
// Zero A-rows contribute nothing, so chaining 4 MFMAs into one acc routes
// tile0 to lanes 0..31 and tile1 to lanes 32..63 with no cross-lane ops.
// D: col=lane&15, row=(lane>>4)*4+reg  (HW-validated in round 2).
__global__ __launch_bounds__(WAVES * 64, 4) void relposenc_mfma3(
    const float* __restrict__ xyz, const float* __restrict__ W1,
    const float* __restrict__ b1,  const float* __restrict__ W2,
    const float* __restrict__ b2,  float* __restrict__ out, int N) {

  __shared__ float sW1b1[4][HID];   // rows 0-2: W1, row 3: b1
  __shared__ float sU[IT][HID];     // u_i (no bias)

  const int tid  = threadIdx.x;
  const int wave = tid >> 6;
  const int lane = tid & 63;
  const int col  = lane & 15;
  const int hgrp = lane >> 4;       // 0..3: k-slice group for A/B frags
  const int b    = blockIdx.z;
  const int i0   = blockIdx.y * IT;
  const int j0   = blockIdx.x * JT + wave * JTW;

  const float* xb = xyz + (size_t)b * 3 * N;

  // ---- stage W1/b1 into LDS ----
  if (tid < 4 * HID) {
    int r = tid >> 6, h = tid & 63;
    sW1b1[r][h] = (r < 3) ? W1[r * HID + h] : b1[h];
  }
  // ---- compute + stage u_i for the block's 16 i's ----
  for (int t = tid; t < IT * HID; t += WAVES * 64) {
    int ii = t >> 6, h = t & 63;
    int i  = i0 + ii;
    sU[ii][h] = fmaf(xb[i], W1[h],
                fmaf(xb[N + i], W1[HID + h],
                     xb[2 * N + i] * W1[2 * HID + h]));
  }

  // ---- A fragments: W2^T in low rows (aLo) / high rows (aHi) ----
  bf16x8 aLo[2], aHi[2];
  #pragma unroll
  for (int kb = 0; kb < 2; ++kb)
    #pragma unroll
    for (int e = 0; e < 8; ++e) {
      int h = kb * 32 + hgrp * 8 + e;
      aLo[kb][e] = f2bf((col < NHD)  ? W2[h * NHD + col]        : 0.f);
      aHi[kb][e] = f2bf((col >= NHD) ? W2[h * NHD + (col - 8)]  : 0.f);
    }
  // ---- per-lane b2: k = ((lane>>4)&1)*4 + r for all lanes ----
  float b2v[4];
  #pragma unroll
  for (int r = 0; r < 4; ++r) b2v[r] = b2[((hgrp & 1) << 2) + r];

  __syncthreads();

  // ---- per-lane a_j = u_j + b1 at this lane's h-slices, for its 2 j's ----
  float aj[2][2][8];
  #pragma unroll
  for (int t = 0; t < 2; ++t) {
    int j = j0 + t * 16 + col;
    float x0 = xb[j], x1 = xb[N + j], x2 = xb[2 * N + j];
    #pragma unroll
    for (int kb = 0; kb < 2; ++kb)
      #pragma unroll
      for (int e = 0; e < 8; ++e) {
        int h = kb * 32 + hgrp * 8 + e;
        aj[t][kb][e] = fmaf(x0, sW1b1[0][h],
                       fmaf(x1, sW1b1[1][h],
                       fmaf(x2, sW1b1[2][h], sW1b1[3][h])));
      }
  }

  // store column: lanes 0-31 -> tile0 j's, lanes 32-63 -> tile1 j's
  const size_t jj = (size_t)j0 + col + ((size_t)(lane >> 5) << 4);
  const int kbase = (hgrp & 1) << 2;
  float* outp = out + ((size_t)(b * NHD + kbase) * N) * N + jj;
  const size_t planeStride = (size_t)N * N;

  // ---- main i-loop, ui software-pipelined one iteration ahead ----
  const float4* pu = (const float4*)(&sU[0][0]);
  float4 nu0 = pu[hgrp * 2],     nu1 = pu[hgrp * 2 + 1];
  float4 nu2 = pu[8 + hgrp * 2], nu3 = pu[8 + hgrp * 2 + 1];

  for (int ii = 0; ii < IT; ++ii) {
    float4 u0 = nu0, u1 = nu1, u2 = nu2, u3 = nu3;
    if (ii + 1 < IT) {
      const float4* pn = (const float4*)(&sU[ii + 1][0]);
      nu0 = pn[hgrp * 2];     nu1 = pn[hgrp * 2 + 1];
      nu2 = pn[8 + hgrp * 2]; nu3 = pn[8 + hgrp * 2 + 1];
    }
    float ui[2][8] = {{u0.x,u0.y,u0.z,u0.w, u1.x,u1.y,u1.z,u1.w},
                      {u2.x,u2.y,u2.z,u2.w, u3.x,u3.y,u3.z,u3.w}};

    bf16x8 bf[2][2];
    #pragma unroll
    for (int t = 0; t < 2; ++t)
      #pragma unroll
      for (int kb = 0; kb < 2; ++kb)
        #pragma unroll
        for (int e = 0; e < 8; ++e) {
          float v = aj[t][kb][e] - ui[kb][e];
          bf[t][kb][e] = f2bf(v > 0.f ? v : 0.f);
        }

    f32x4 c = {0.f, 0.f, 0.f, 0.f};
    c = __builtin_amdgcn_mfma_f32_16x16x32_bf16(aLo[0], bf[0][0], c, 0, 0, 0);
    c = __builtin_amdgcn_mfma_f32_16x16x32_bf16(aLo[1], bf[0][1], c, 0, 0, 0);
    c = __builtin_amdgcn_mfma_f32_16x16x32_bf16(aHi[0], bf[1][0], c, 0, 0, 0);
    c = __builtin_amdgcn_mfma_f32_16x16x32_bf16(aHi[1], bf[1][1], c, 0, 0, 0);

    float* p = outp + (size_t)(i0 + ii) * N;
    #pragma unroll
    for (int r = 0; r < 4; ++r) {
      __builtin_nontemporal_store(c[r] + b2v[r], p + (size_t)r * planeStride);
    }
  }
}

extern "C" void kernel_launch(void* const* d_in, const int* in_sizes, int n_in,
                              void* d_out, int out_size, void* d_ws, size_t ws_size,
                              hipStream_t stream) {
  const float* xyz = (const float*)d_in[0];
  const float* W1  = (const float*)d_in[1];
  const float* b1  = (const float*)d_in[2];
  const float* W2  = (const float*)d_in[3];
  const float* b2  = (const float*)d_in[4];
  float* out = (float*)d_out;

  const long long in0 = in_sizes[0];
  const int N = (int)((3LL * (long long)out_size) / (8LL * in0));
  const int B = (int)(in0 / (3LL * N));

  dim3 grid(N / JT, N / IT, B);
  relposenc_mfma3<<<grid, WAVES * 64, 0, stream>>>(xyz, W1, b1, W2, b2, out, N);
}

// Round 5
// 24.284 us; speedup vs baseline: 1.1703x; 1.1703x over previous
//
#include <hip/hip_runtime.h>
#include <hip/hip_bf16.h>

#define HID   64
#define NHD   8
#define IT    16          // i's per block
#define WAVES 8
#define JTW   32          // j's per wave (2 MFMA tiles of 16)
#define JT    (WAVES*JTW) // 256 j's per block

typedef _Float16 f16x8 __attribute__((ext_vector_type(8)));
typedef float    f32x4 __attribute__((ext_vector_type(4)));

// out[b,k,i,j] = sum_h relu( (u_j[h]+b1[h]) - u_i[h] ) * W2[h,k] + b2[k]
// Packed-fp16 pipeline: aj/ui/relu-diff all f16x8 (v_pk_add/v_pk_max), feeding
// mfma_f32_16x16x32_f16 directly (no cvt). aLo = W2^T in A-rows 0..7, aHi in
// rows 8..15 (zero elsewhere): D rows 0..7 = j-tile0, rows 8..15 = j-tile1
// (HW-validated round 4), so all 64 lanes store useful data: 4 plain stores/i,
// each two full 128B lines. Two independent MFMA chains cA/cB for ILP.
__global__ __launch_bounds__(WAVES * 64, 4) void relposenc_f16(
    const float* __restrict__ xyz, const float* __restrict__ W1,
    const float* __restrict__ b1,  const float* __restrict__ W2,
    const float* __restrict__ b2,  float* __restrict__ out, int N) {

  __shared__ float    sW1b1[4][HID];   // rows 0-2: W1, row 3: b1
  __shared__ _Float16 sU[IT][HID];     // u_i (no bias), packed f16

  const int tid  = threadIdx.x;
  const int wave = tid >> 6;
  const int lane = tid & 63;
  const int col  = lane & 15;
  const int hgrp = lane >> 4;       // 0..3: k-slice group for A/B frags
  const int b    = blockIdx.z;
  const int i0   = blockIdx.y * IT;
  const int j0   = blockIdx.x * JT + wave * JTW;

  const float* xb = xyz + (size_t)b * 3 * N;

  // ---- stage W1/b1 into LDS ----
  if (tid < 4 * HID) {
    int r = tid >> 6, h = tid & 63;
    sW1b1[r][h] = (r < 3) ? W1[r * HID + h] : b1[h];
  }
  // ---- compute + stage u_i (f16) for the block's 16 i's ----
  for (int t = tid; t < IT * HID; t += WAVES * 64) {
    int ii = t >> 6, h = t & 63;
    int i  = i0 + ii;
    float u = fmaf(xb[i], W1[h],
              fmaf(xb[N + i], W1[HID + h],
                   xb[2 * N + i] * W1[2 * HID + h]));
    sU[ii][h] = (_Float16)u;
  }

  // ---- A fragments (f16): W2^T in low rows (aLo) / high rows (aHi) ----
  f16x8 aLo[2], aHi[2];
  #pragma unroll
  for (int kb = 0; kb < 2; ++kb)
    #pragma unroll
    for (int e = 0; e < 8; ++e) {
      int h = kb * 32 + hgrp * 8 + e;
      aLo[kb][e] = (_Float16)((col < NHD)  ? W2[h * NHD + col]       : 0.f);
      aHi[kb][e] = (_Float16)((col >= NHD) ? W2[h * NHD + (col - 8)] : 0.f);
    }
  // ---- per-lane b2: k = ((lane>>4)&1)*4 + r ----
  float b2v[4];
  #pragma unroll
  for (int r = 0; r < 4; ++r) b2v[r] = b2[((hgrp & 1) << 2) + r];

  __syncthreads();

  // ---- per-lane a_j = u_j + b1 (f16-packed) for this lane's 2 j's ----
  f16x8 aj[2][2];
  #pragma unroll
  for (int t = 0; t < 2; ++t) {
    int j = j0 + t * 16 + col;
    float x0 = xb[j], x1 = xb[N + j], x2 = xb[2 * N + j];
    #pragma unroll
    for (int kb = 0; kb < 2; ++kb)
      #pragma unroll
      for (int e = 0; e < 8; ++e) {
        int h = kb * 32 + hgrp * 8 + e;
        float v = fmaf(x0, sW1b1[0][h],
                  fmaf(x1, sW1b1[1][h],
                  fmaf(x2, sW1b1[2][h], sW1b1[3][h])));
        aj[t][kb][e] = (_Float16)v;
      }
  }

  // store column: lanes 0-31 -> tile0 j's, lanes 32-63 -> tile1 j's
  const size_t jj = (size_t)j0 + col + ((size_t)(lane >> 5) << 4);
  const int kbase = (hgrp & 1) << 2;
  float* outp = out + ((size_t)(b * NHD + kbase) * N + i0) * N + jj;
  const size_t plane = (size_t)N * N;

  const f16x8 z = {0, 0, 0, 0, 0, 0, 0, 0};

  // ---- main i-loop, ui (2 x ds_read_b128) software-pipelined 1 ahead ----
  f16x8 nu0 = *(const f16x8*)&sU[0][hgrp * 8];
  f16x8 nu1 = *(const f16x8*)&sU[0][32 + hgrp * 8];

  for (int ii = 0; ii < IT; ++ii) {
    f16x8 u0 = nu0, u1 = nu1;
    if (ii + 1 < IT) {
      nu0 = *(const f16x8*)&sU[ii + 1][hgrp * 8];
      nu1 = *(const f16x8*)&sU[ii + 1][32 + hgrp * 8];
    }

    // relu-diff fragments: v_pk_add_f16(neg) + v_pk_max_f16
    f16x8 d00 = __builtin_elementwise_max(aj[0][0] - u0, z);
    f16x8 d01 = __builtin_elementwise_max(aj[0][1] - u1, z);
    f16x8 d10 = __builtin_elementwise_max(aj[1][0] - u0, z);
    f16x8 d11 = __builtin_elementwise_max(aj[1][1] - u1, z);

    f32x4 cA = {0.f, 0.f, 0.f, 0.f}, cB = {0.f, 0.f, 0.f, 0.f};
    cA = __builtin_amdgcn_mfma_f32_16x16x32_f16(aLo[0], d00, cA, 0, 0, 0);
    cA = __builtin_amdgcn_mfma_f32_16x16x32_f16(aLo[1], d01, cA, 0, 0, 0);
    cB = __builtin_amdgcn_mfma_f32_16x16x32_f16(aHi[0], d10, cB, 0, 0, 0);
    cB = __builtin_amdgcn_mfma_f32_16x16x32_f16(aHi[1], d11, cB, 0, 0, 0);

    float* p = outp + (size_t)ii * N;
    #pragma unroll
    for (int r = 0; r < 4; ++r) {
      p[(size_t)r * plane] = cA[r] + cB[r] + b2v[r];
    }
  }
}

extern "C" void kernel_launch(void* const* d_in, const int* in_sizes, int n_in,
                              void* d_out, int out_size, void* d_ws, size_t ws_size,
                              hipStream_t stream) {
  const float* xyz = (const float*)d_in[0];
  const float* W1  = (const float*)d_in[1];
  const float* b1  = (const float*)d_in[2];
  const float* W2  = (const float*)d_in[3];
  const float* b2  = (const float*)d_in[4];
  float* out = (float*)d_out;

  const long long in0 = in_sizes[0];
  const int N = (int)((3LL * (long long)out_size) / (8LL * in0));
  const int B = (int)(in0 / (3LL * N));

  dim3 grid(N / JT, N / IT, B);
  relposenc_f16<<<grid, WAVES * 64, 0, stream>>>(xyz, W1, b1, W2, b2, out, N);
}